// Round 1
// baseline (1562.758 us; speedup 1.0000x reference)
//
#include <hip/hip_runtime.h>
#include <math.h>

#define SEQ 4096
#define DIM 1024
#define DHEAD 256
#define NHEADS 4

// ---------------------------------------------------------------------------
// K1: qkv[n] = x @ Wq[n]   (x: [4096,1024], Wq[n]: [1024,256] -> qkv[n]:[4096,256])
// grid (64, 4, 4)  block 256; 64x64 tile, BK=16, 4x4 per thread
// ---------------------------------------------------------------------------
__global__ __launch_bounds__(256)
void qkv_gemm_kernel(const float* __restrict__ x, const float* __restrict__ Wq,
                     float* __restrict__ qkv) {
    __shared__ float As[16][68];   // [k][m], +4 pad keeps b128 aligned & banks spread
    __shared__ float Bs[16][68];   // [k][n]
    const int tid = threadIdx.x;
    const int ty = tid >> 4, tx = tid & 15;
    const int m0 = blockIdx.x * 64;
    const int n0 = blockIdx.y * 64;
    const int head = blockIdx.z;
    const float* __restrict__ B = Wq + (size_t)head * DIM * DHEAD;

    float acc[4][4];
#pragma unroll
    for (int r = 0; r < 4; ++r)
#pragma unroll
        for (int c = 0; c < 4; ++c) acc[r][c] = 0.f;

    const int ar = tid >> 2, ac = tid & 3;    // A: 64 rows x 4 float4
    const int br = tid >> 4, bc = tid & 15;   // B: 16 rows x 16 float4

    for (int kb = 0; kb < DIM; kb += 16) {
        const float4 av = *(const float4*)&x[(size_t)(m0 + ar) * DIM + kb + ac * 4];
        const float4 bv = *(const float4*)&B[(size_t)(kb + br) * DHEAD + n0 + bc * 4];
        __syncthreads();
        As[ac * 4 + 0][ar] = av.x; As[ac * 4 + 1][ar] = av.y;
        As[ac * 4 + 2][ar] = av.z; As[ac * 4 + 3][ar] = av.w;
        *(float4*)&Bs[br][bc * 4] = bv;
        __syncthreads();
#pragma unroll
        for (int k = 0; k < 16; ++k) {
            const float4 a = *(const float4*)&As[k][ty * 4];
            const float4 b = *(const float4*)&Bs[k][tx * 4];
            const float a4[4] = {a.x, a.y, a.z, a.w};
            const float b4[4] = {b.x, b.y, b.z, b.w};
#pragma unroll
            for (int r = 0; r < 4; ++r)
#pragma unroll
                for (int c = 0; c < 4; ++c) acc[r][c] += a4[r] * b4[c];
        }
    }
    float* __restrict__ out = qkv + (size_t)head * SEQ * DHEAD;
#pragma unroll
    for (int r = 0; r < 4; ++r) {
        float4 o; o.x = acc[r][0]; o.y = acc[r][1]; o.z = acc[r][2]; o.w = acc[r][3];
        *(float4*)&out[(size_t)(m0 + ty * 4 + r) * DHEAD + n0 + tx * 4] = o;
    }
}

// ---------------------------------------------------------------------------
// K2: flash attention per head (Q=K=V=qkv[head]), softmax over keys, no scale.
// grid (64, 4) block 256. Block = 64 q-rows; loop 64-key tiles.
// Qs/Ks stored row-major with XOR swizzle on float4 column-groups:
//   element (row, c) lives at float col ((c>>2) ^ ((row>>2)&7))*4 + (c&3)
// -> conflict-free for both k-major S reads and row-major PV reads.
// ---------------------------------------------------------------------------
__global__ __launch_bounds__(256, 1)
void attn_kernel(const float* __restrict__ qkv, float* __restrict__ zc) {
    __shared__ float Qs[64][256];
    __shared__ float Ks[64][256];
    __shared__ float Ps[64][68];

    const int tid = threadIdx.x;
    const int ty = tid >> 4;   // 0..15 -> rows ty*4..+4
    const int tx = tid & 15;   // 0..15 -> S cols tx*4..+4 ; O col-groups tx+16*i
    const int qb = blockIdx.x;
    const int head = blockIdx.y;
    const float* __restrict__ base = qkv + (size_t)head * SEQ * DHEAD;

    // stage Q once (64 rows x 256), swizzled
#pragma unroll
    for (int i = 0; i < 16; ++i) {
        const int f = tid + 256 * i;
        const int row = f >> 6;
        const int cg = f & 63;
        const float4 v = *(const float4*)&base[(size_t)(qb * 64 + row) * DHEAD + cg * 4];
        const int scg = cg ^ ((row >> 2) & 7);
        *(float4*)&Qs[row][scg * 4] = v;
    }

    float m[4], l[4], acc[4][16];
#pragma unroll
    for (int r = 0; r < 4; ++r) {
        m[r] = -INFINITY; l[r] = 0.f;
#pragma unroll
        for (int c = 0; c < 16; ++c) acc[r][c] = 0.f;
    }

    for (int jb = 0; jb < SEQ; jb += 64) {
        __syncthreads();   // previous PV done with Ks/Ps
#pragma unroll
        for (int i = 0; i < 16; ++i) {
            const int f = tid + 256 * i;
            const int row = f >> 6;
            const int cg = f & 63;
            const float4 v = *(const float4*)&base[(size_t)(jb + row) * DHEAD + cg * 4];
            const int scg = cg ^ ((row >> 2) & 7);
            *(float4*)&Ks[row][scg * 4] = v;
        }
        __syncthreads();

        // ---- S = Q @ Ktile^T, full k=256, 4x4 per thread ----
        float s[4][4];
#pragma unroll
        for (int r = 0; r < 4; ++r)
#pragma unroll
            for (int j = 0; j < 4; ++j) s[r][j] = 0.f;

#pragma unroll 4
        for (int kc = 0; kc < 64; ++kc) {
            float4 qa[4], kv[4];
#pragma unroll
            for (int r = 0; r < 4; ++r)
                qa[r] = *(const float4*)&Qs[ty * 4 + r][(kc ^ (ty & 7)) * 4];
#pragma unroll
            for (int j = 0; j < 4; ++j)
                kv[j] = *(const float4*)&Ks[tx * 4 + j][(kc ^ (tx & 7)) * 4];
#pragma unroll
            for (int r = 0; r < 4; ++r)
#pragma unroll
                for (int j = 0; j < 4; ++j)
                    s[r][j] += qa[r].x * kv[j].x + qa[r].y * kv[j].y +
                               qa[r].z * kv[j].z + qa[r].w * kv[j].w;
        }

        // ---- online softmax (rows shared by the 16 tx lanes of this ty group) ----
        float mx[4];
#pragma unroll
        for (int r = 0; r < 4; ++r)
            mx[r] = fmaxf(fmaxf(s[r][0], s[r][1]), fmaxf(s[r][2], s[r][3]));
#pragma unroll
        for (int off = 1; off < 16; off <<= 1)
#pragma unroll
            for (int r = 0; r < 4; ++r)
                mx[r] = fmaxf(mx[r], __shfl_xor(mx[r], off, 64));

        float alpha[4], rs[4];
#pragma unroll
        for (int r = 0; r < 4; ++r) {
            const float mn = fmaxf(m[r], mx[r]);
            alpha[r] = __expf(m[r] - mn);
            m[r] = mn;
#pragma unroll
            for (int j = 0; j < 4; ++j) s[r][j] = __expf(s[r][j] - mn);
            rs[r] = (s[r][0] + s[r][1]) + (s[r][2] + s[r][3]);
        }
#pragma unroll
        for (int off = 1; off < 16; off <<= 1)
#pragma unroll
            for (int r = 0; r < 4; ++r)
                rs[r] += __shfl_xor(rs[r], off, 64);

#pragma unroll
        for (int r = 0; r < 4; ++r) {
            l[r] = l[r] * alpha[r] + rs[r];
#pragma unroll
            for (int c = 0; c < 16; ++c) acc[r][c] *= alpha[r];
            float4 pv; pv.x = s[r][0]; pv.y = s[r][1]; pv.z = s[r][2]; pv.w = s[r][3];
            *(float4*)&Ps[ty * 4 + r][tx * 4] = pv;
        }
        __syncthreads();

        // ---- O += P @ Vtile (V = Ks rows) ----
#pragma unroll 2
        for (int j = 0; j < 64; ++j) {
            const int sj = (j >> 2) & 7;
            float pr[4];
#pragma unroll
            for (int r = 0; r < 4; ++r) pr[r] = Ps[ty * 4 + r][j];
            float4 vv[4];
#pragma unroll
            for (int i = 0; i < 4; ++i)
                vv[i] = *(const float4*)&Ks[j][((tx + 16 * i) ^ sj) * 4];
#pragma unroll
            for (int r = 0; r < 4; ++r)
#pragma unroll
                for (int i = 0; i < 4; ++i) {
                    acc[r][i * 4 + 0] += pr[r] * vv[i].x;
                    acc[r][i * 4 + 1] += pr[r] * vv[i].y;
                    acc[r][i * 4 + 2] += pr[r] * vv[i].z;
                    acc[r][i * 4 + 3] += pr[r] * vv[i].w;
                }
        }
    }

    // epilogue: normalize, write zc[row][head*256 + col]
#pragma unroll
    for (int r = 0; r < 4; ++r) {
        const float inv = 1.0f / l[r];
        const size_t row = (size_t)(qb * 64 + ty * 4 + r);
#pragma unroll
        for (int i = 0; i < 4; ++i) {
            float4 o;
            o.x = acc[r][i * 4 + 0] * inv; o.y = acc[r][i * 4 + 1] * inv;
            o.z = acc[r][i * 4 + 2] * inv; o.w = acc[r][i * 4 + 3] * inv;
            *(float4*)&zc[row * (NHEADS * DHEAD) + head * DHEAD + (tx + 16 * i) * 4] = o;
        }
    }
}

// ---------------------------------------------------------------------------
// K3: out = zc @ lin_w^T + lin_b   (zc:[4096,1024], lin_w:[1024,1024] row=out)
// grid (64, 16) block 256; both A and B read contiguous along k.
// ---------------------------------------------------------------------------
__global__ __launch_bounds__(256)
void out_gemm_kernel(const float* __restrict__ zc, const float* __restrict__ lw,
                     const float* __restrict__ lb, float* __restrict__ out) {
    __shared__ float As[16][68];
    __shared__ float Bs[16][68];
    const int tid = threadIdx.x;
    const int ty = tid >> 4, tx = tid & 15;
    const int m0 = blockIdx.x * 64;
    const int n0 = blockIdx.y * 64;

    float acc[4][4];
#pragma unroll
    for (int r = 0; r < 4; ++r)
#pragma unroll
        for (int c = 0; c < 4; ++c) acc[r][c] = 0.f;

    const int r8 = tid >> 2, c4 = tid & 3;   // 64 rows x 4 float4 along k

    for (int kb = 0; kb < DIM; kb += 16) {
        const float4 av = *(const float4*)&zc[(size_t)(m0 + r8) * DIM + kb + c4 * 4];
        const float4 bv = *(const float4*)&lw[(size_t)(n0 + r8) * DIM + kb + c4 * 4];
        __syncthreads();
        As[c4 * 4 + 0][r8] = av.x; As[c4 * 4 + 1][r8] = av.y;
        As[c4 * 4 + 2][r8] = av.z; As[c4 * 4 + 3][r8] = av.w;
        Bs[c4 * 4 + 0][r8] = bv.x; Bs[c4 * 4 + 1][r8] = bv.y;
        Bs[c4 * 4 + 2][r8] = bv.z; Bs[c4 * 4 + 3][r8] = bv.w;
        __syncthreads();
#pragma unroll
        for (int k = 0; k < 16; ++k) {
            const float4 a = *(const float4*)&As[k][ty * 4];
            const float4 b = *(const float4*)&Bs[k][tx * 4];
            const float a4[4] = {a.x, a.y, a.z, a.w};
            const float b4[4] = {b.x, b.y, b.z, b.w};
#pragma unroll
            for (int r = 0; r < 4; ++r)
#pragma unroll
                for (int c = 0; c < 4; ++c) acc[r][c] += a4[r] * b4[c];
        }
    }
    const float4 bias = *(const float4*)&lb[n0 + tx * 4];
    const float b4[4] = {bias.x, bias.y, bias.z, bias.w};
#pragma unroll
    for (int r = 0; r < 4; ++r) {
        float4 o;
        o.x = acc[r][0] + b4[0]; o.y = acc[r][1] + b4[1];
        o.z = acc[r][2] + b4[2]; o.w = acc[r][3] + b4[3];
        *(float4*)&out[(size_t)(m0 + ty * 4 + r) * DIM + n0 + tx * 4] = o;
    }
}

// ---------------------------------------------------------------------------
extern "C" void kernel_launch(void* const* d_in, const int* in_sizes, int n_in,
                              void* d_out, int out_size, void* d_ws, size_t ws_size,
                              hipStream_t stream) {
    const float* x  = (const float*)d_in[0];   // [4096,1024]
    const float* Wq = (const float*)d_in[1];   // [4,1024,256]
    const float* lw = (const float*)d_in[2];   // [1024,1024]
    const float* lb = (const float*)d_in[3];   // [1024]
    float* out = (float*)d_out;                // [4096,1024]

    float* qkv = (float*)d_ws;                                  // 16 MB
    float* zc  = (float*)d_ws + (size_t)NHEADS * SEQ * DHEAD;   // 16 MB

    qkv_gemm_kernel<<<dim3(SEQ / 64, DHEAD / 64, NHEADS), 256, 0, stream>>>(x, Wq, qkv);
    attn_kernel<<<dim3(SEQ / 64, NHEADS), 256, 0, stream>>>(qkv, zc);
    out_gemm_kernel<<<dim3(SEQ / 64, DIM / 64), 256, 0, stream>>>(zc, lw, lb, out);
}

// Round 2
// 250.507 us; speedup vs baseline: 6.2384x; 6.2384x over previous
//
#include <hip/hip_runtime.h>
#include <math.h>

#define SEQ 4096
#define DIM 1024
#define DHEAD 256
#define NHEADS 4

typedef __attribute__((ext_vector_type(8))) short bf16x8;
typedef __attribute__((ext_vector_type(4))) float f32x4;
typedef __attribute__((ext_vector_type(4))) short short4v;
typedef __attribute__((ext_vector_type(8))) short short8v;

// fp32 -> bf16 round-to-nearest-even, as raw ushort bits
__device__ __forceinline__ unsigned short f2b(float f) {
    union { float f; unsigned u; } v; v.f = f;
    unsigned r = v.u + 0x7FFFu + ((v.u >> 16) & 1u);
    return (unsigned short)(r >> 16);
}

// async global->LDS, 16B per lane; lds must be wave-uniform base, g is per-lane
__device__ __forceinline__ void gll16(const void* g, void* lds) {
    __builtin_amdgcn_global_load_lds(
        (const __attribute__((address_space(1))) unsigned*)g,
        (__attribute__((address_space(3))) unsigned*)lds, 16, 0, 0);
}

__device__ __forceinline__ f32x4 mfma16(bf16x8 a, bf16x8 b, f32x4 c) {
    return __builtin_amdgcn_mfma_f32_16x16x32_bf16(a, b, c, 0, 0, 0);
}

// ---------------------------------------------------------------------------
// convert fp32 -> bf16, n4 float4's
// ---------------------------------------------------------------------------
__global__ __launch_bounds__(256)
void conv_kernel(const float* __restrict__ in, unsigned short* __restrict__ out, int n4) {
    int i = blockIdx.x * 256 + threadIdx.x;
    if (i >= n4) return;
    float4 v = ((const float4*)in)[i];
    short4v o;
    o[0] = (short)f2b(v.x); o[1] = (short)f2b(v.y);
    o[2] = (short)f2b(v.z); o[3] = (short)f2b(v.w);
    *(short4v*)(out + (size_t)i * 4) = o;
}

// ---------------------------------------------------------------------------
// Wq [4][1024][256] fp32 -> WqT [4][256][1024] bf16 (transpose d<->c per head)
// grid (16, 4, 4): bx = d-block, by = c-block, bz = head. 64x64 tiles.
// ---------------------------------------------------------------------------
__global__ __launch_bounds__(256)
void wqt_kernel(const float* __restrict__ Wq, unsigned short* __restrict__ WqT) {
    __shared__ unsigned short T[64][72];
    const int tid = threadIdx.x;
    const int h = blockIdx.z;
    const int d0 = blockIdx.x * 64, c0 = blockIdx.y * 64;
#pragma unroll
    for (int it = 0; it < 4; ++it) {
        int f = tid + 256 * it;           // 1024 float4
        int row = f >> 4, cg = f & 15;    // row = d offset, 16 float4 per row
        float4 v = *(const float4*)&Wq[((size_t)(h * DIM + d0 + row)) * DHEAD + c0 + cg * 4];
        T[row][cg * 4 + 0] = f2b(v.x); T[row][cg * 4 + 1] = f2b(v.y);
        T[row][cg * 4 + 2] = f2b(v.z); T[row][cg * 4 + 3] = f2b(v.w);
    }
    __syncthreads();
#pragma unroll
    for (int it = 0; it < 2; ++it) {
        int f = tid + 256 * it;           // 512 short8
        int cl = f >> 3, dg = f & 7;
        short8v o;
#pragma unroll
        for (int e = 0; e < 8; ++e) o[e] = (short)T[dg * 8 + e][cl];
        *(short8v*)&WqT[((size_t)(h * DHEAD + c0 + cl)) * DIM + d0 + dg * 8] = o;
    }
}

// ---------------------------------------------------------------------------
// qkv [4][4096][256] bf16 -> qkvT [4][256][4096] bf16
// grid (64, 4, 4): bx = seq-block, by = d-block, bz = head
// ---------------------------------------------------------------------------
__global__ __launch_bounds__(256)
void qkvt_kernel(const unsigned short* __restrict__ qkv, unsigned short* __restrict__ qkvT) {
    __shared__ unsigned short T[64][72];
    const int tid = threadIdx.x;
    const int h = blockIdx.z;
    const int r0 = blockIdx.x * 64, c0 = blockIdx.y * 64;
#pragma unroll
    for (int it = 0; it < 2; ++it) {
        int f = tid + 256 * it;           // 512 short8
        int row = f >> 3, cg = f & 7;
        short8v v = *(const short8v*)&qkv[((size_t)h * SEQ + r0 + row) * DHEAD + c0 + cg * 8];
#pragma unroll
        for (int e = 0; e < 8; ++e) T[row][cg * 8 + e] = (unsigned short)v[e];
    }
    __syncthreads();
#pragma unroll
    for (int it = 0; it < 2; ++it) {
        int f = tid + 256 * it;
        int cl = f >> 3, rg = f & 7;
        short8v o;
#pragma unroll
        for (int e = 0; e < 8; ++e) o[e] = (short)T[rg * 8 + e][cl];
        *(short8v*)&qkvT[((size_t)h * DHEAD + c0 + cl) * SEQ + r0 + rg * 8] = o;
    }
}

// ---------------------------------------------------------------------------
// K1: qkv = x @ Wq  as bf16 MFMA GEMM.  A = x_b [4096][1024], B = WqT [1024][1024]
// (flat row n = h*256+c, contiguous k). Out: qkv bf16 [4][4096][256].
// BM=BN=128, BK=64, 4 waves, each 64x64 (4x4 tiles of 16x16x32).
// LDS rows of 64 bf16 = 8 x 16B chunks, stored chunk = c ^ (row&7).
// ---------------------------------------------------------------------------
__global__ __launch_bounds__(256)
void qkv_gemm_kernel(const unsigned short* __restrict__ A,
                     const unsigned short* __restrict__ B,
                     unsigned short* __restrict__ qkv) {
    __shared__ unsigned short As[128 * 64];
    __shared__ unsigned short Bs[128 * 64];
    const int tid = threadIdx.x, w = tid >> 6, l = tid & 63;
    const int g = l >> 4, r16 = l & 15;
    const int m0 = blockIdx.x * 128, n0 = blockIdx.y * 128;
    const int wm = (w >> 1) * 64, wn = (w & 1) * 64;

    f32x4 acc[4][4];
#pragma unroll
    for (int mr = 0; mr < 4; ++mr)
#pragma unroll
        for (int nr = 0; nr < 4; ++nr) acc[mr][nr] = (f32x4){0.f, 0.f, 0.f, 0.f};

    for (int kb = 0; kb < DIM; kb += 64) {
        __syncthreads();
#pragma unroll
        for (int cc = 0; cc < 4; ++cc) {
            int row = w * 32 + cc * 8 + (l >> 3);
            int c = (l & 7) ^ (row & 7);
            gll16(&A[(size_t)(m0 + row) * DIM + kb + c * 8], &As[(size_t)(w * 32 + cc * 8) * 64]);
            gll16(&B[(size_t)(n0 + row) * DIM + kb + c * 8], &Bs[(size_t)(w * 32 + cc * 8) * 64]);
        }
        __syncthreads();
#pragma unroll
        for (int s = 0; s < 2; ++s) {
            bf16x8 af[4], bf[4];
#pragma unroll
            for (int mr = 0; mr < 4; ++mr) {
                int row = wm + mr * 16 + r16;
                int st = (s * 4 + g) ^ (row & 7);
                af[mr] = *(const bf16x8*)&As[row * 64 + st * 8];
            }
#pragma unroll
            for (int nr = 0; nr < 4; ++nr) {
                int row = wn + nr * 16 + r16;
                int st = (s * 4 + g) ^ (row & 7);
                bf[nr] = *(const bf16x8*)&Bs[row * 64 + st * 8];
            }
#pragma unroll
            for (int mr = 0; mr < 4; ++mr)
#pragma unroll
                for (int nr = 0; nr < 4; ++nr)
                    acc[mr][nr] = mfma16(af[mr], bf[nr], acc[mr][nr]);
        }
    }
#pragma unroll
    for (int mr = 0; mr < 4; ++mr)
#pragma unroll
        for (int nr = 0; nr < 4; ++nr) {
            int n = n0 + wn + nr * 16 + r16;
            int h = n >> 8, c = n & 255;
#pragma unroll
            for (int r = 0; r < 4; ++r) {
                int m = m0 + wm + mr * 16 + g * 4 + r;
                qkv[((size_t)h * SEQ + m) * DHEAD + c] = f2b(acc[mr][nr][r]);
            }
        }
}

// ---------------------------------------------------------------------------
// K2: MFMA flash attention. grid (64, 4) = (q-block, head), 256 thr, 4 waves.
// QBLK=64, KBLK=64. Wave w: QK^T on q-strip [16w,16w+16) x all 64 j;
// PV on ALL 64 q x d-slice [64w, 64w+64)  (alpha/l shared via LDS).
// Q fragments live in registers for the whole kernel.
// ---------------------------------------------------------------------------
__global__ __launch_bounds__(256, 1)
void attn_kernel(const unsigned short* __restrict__ qkv,
                 const unsigned short* __restrict__ qkvT,
                 unsigned short* __restrict__ zc) {
    __shared__ unsigned short Ks[64 * 256];  // row j: 32 chunks, st=(c&24)|((c&7)^(j&7))
    __shared__ unsigned short Vt[256 * 64];  // row d: 8 chunks, st=c^(d&7)
    __shared__ unsigned short Ps[64 * 64];   // row q: 8 chunks, st=c^(q&7)
    __shared__ float alphaS[64];
    __shared__ float lS[64];

    const int tid = threadIdx.x, w = tid >> 6, l = tid & 63;
    const int g = l >> 4, r16 = l & 15;
    const int h = blockIdx.y, qb = blockIdx.x;
    const unsigned short* __restrict__ qh = qkv + (size_t)h * SEQ * DHEAD;
    const unsigned short* __restrict__ qth = qkvT + (size_t)h * DHEAD * SEQ;

    // Q fragments: lane row = qb*64 + w*16 + r16, k-elems s*32 + g*8 .. +8
    bf16x8 qf[8];
    {
        const unsigned short* qrow = qh + (size_t)(qb * 64 + w * 16 + r16) * DHEAD + g * 8;
#pragma unroll
        for (int s = 0; s < 8; ++s) qf[s] = *(const bf16x8*)(qrow + s * 32);
    }

    f32x4 Oacc[16];  // [qs*4+dt]
#pragma unroll
    for (int i = 0; i < 16; ++i) Oacc[i] = (f32x4){0.f, 0.f, 0.f, 0.f};
    float mrow[4], lrow[4];
#pragma unroll
    for (int r = 0; r < 4; ++r) { mrow[r] = -INFINITY; lrow[r] = 0.f; }

    for (int jb = 0; jb < SEQ; jb += 64) {
        __syncthreads();  // prev iter's LDS reads done
        // stage K tile (row-major) and V^T tile, swizzled via per-lane source addr
#pragma unroll
        for (int cc = 0; cc < 8; ++cc) {
            int ch = w * 8 + cc;               // 1KB chunk, 2 rows of K
            int j = ch * 2 + (l >> 5);
            int cp = l & 31;
            int c = (cp & 24) | ((cp & 7) ^ (j & 7));
            gll16(&qh[(size_t)(jb + j) * DHEAD + c * 8], &Ks[(size_t)ch * 512]);
        }
#pragma unroll
        for (int cc = 0; cc < 8; ++cc) {
            int ch = w * 8 + cc;               // 1KB chunk, 8 rows of Vt
            int d = ch * 8 + (l >> 3);
            int c = (l & 7) ^ (d & 7);
            gll16(&qth[(size_t)d * SEQ + jb + c * 8], &Vt[(size_t)ch * 512]);
        }
        __syncthreads();  // all staging visible (syncthreads drains vmcnt)

        // ---- S = Q @ K^T on this wave's 16-row strip ----
        f32x4 sacc[4];
#pragma unroll
        for (int jt = 0; jt < 4; ++jt) sacc[jt] = (f32x4){0.f, 0.f, 0.f, 0.f};
#pragma unroll
        for (int s = 0; s < 8; ++s) {
#pragma unroll
            for (int jt = 0; jt < 4; ++jt) {
                int j = jt * 16 + r16;
                int c = s * 4 + g;
                int st = (c & 24) | ((c & 7) ^ (j & 7));
                bf16x8 kf = *(const bf16x8*)&Ks[j * 256 + st * 8];
                sacc[jt] = mfma16(qf[s], kf, sacc[jt]);
            }
        }

        // ---- online softmax: rows q = w*16 + g*4 + r, cols across r16 lanes ----
        float mx[4];
#pragma unroll
        for (int r = 0; r < 4; ++r)
            mx[r] = fmaxf(fmaxf(sacc[0][r], sacc[1][r]), fmaxf(sacc[2][r], sacc[3][r]));
#pragma unroll
        for (int off = 1; off < 16; off <<= 1)
#pragma unroll
            for (int r = 0; r < 4; ++r) mx[r] = fmaxf(mx[r], __shfl_xor(mx[r], off, 64));

        float alpha[4], rsum[4];
#pragma unroll
        for (int r = 0; r < 4; ++r) {
            float mn = fmaxf(mrow[r], mx[r]);
            alpha[r] = __expf(mrow[r] - mn);
            mrow[r] = mn;
            rsum[r] = 0.f;
        }
#pragma unroll
        for (int jt = 0; jt < 4; ++jt) {
            int j = jt * 16 + r16;
#pragma unroll
            for (int r = 0; r < 4; ++r) {
                int qrow = w * 16 + g * 4 + r;
                float p = __expf(sacc[jt][r] - mrow[r]);
                rsum[r] += p;
                int st = (j >> 3) ^ (qrow & 7);
                Ps[qrow * 64 + st * 8 + (j & 7)] = f2b(p);
            }
        }
#pragma unroll
        for (int off = 1; off < 16; off <<= 1)
#pragma unroll
            for (int r = 0; r < 4; ++r) rsum[r] += __shfl_xor(rsum[r], off, 64);
#pragma unroll
        for (int r = 0; r < 4; ++r) lrow[r] = lrow[r] * alpha[r] + rsum[r];
        if (r16 == 0) {
#pragma unroll
            for (int r = 0; r < 4; ++r) alphaS[w * 16 + g * 4 + r] = alpha[r];
        }
        __syncthreads();  // Ps + alphaS visible

        // ---- O += P @ V on all 64 q-rows x this wave's 64-wide d-slice ----
        bf16x8 pa[8];
#pragma unroll
        for (int qs = 0; qs < 4; ++qs) {
            f32x4 av = *(const f32x4*)&alphaS[qs * 16 + g * 4];
#pragma unroll
            for (int dt = 0; dt < 4; ++dt)
#pragma unroll
                for (int r = 0; r < 4; ++r) Oacc[qs * 4 + dt][r] *= av[r];
#pragma unroll
            for (int s2 = 0; s2 < 2; ++s2) {
                int qrow = qs * 16 + r16;
                int st = (s2 * 4 + g) ^ (qrow & 7);
                pa[qs * 2 + s2] = *(const bf16x8*)&Ps[qrow * 64 + st * 8];
            }
        }
#pragma unroll
        for (int dt = 0; dt < 4; ++dt) {
            int d = w * 64 + dt * 16 + r16;
#pragma unroll
            for (int s2 = 0; s2 < 2; ++s2) {
                int st = (s2 * 4 + g) ^ (d & 7);
                bf16x8 bv = *(const bf16x8*)&Vt[d * 64 + st * 8];
#pragma unroll
                for (int qs = 0; qs < 4; ++qs)
                    Oacc[qs * 4 + dt] = mfma16(pa[qs * 2 + s2], bv, Oacc[qs * 4 + dt]);
            }
        }
    }

    // epilogue: share l, normalize, write zc bf16
    if (r16 == 0) {
#pragma unroll
        for (int r = 0; r < 4; ++r) lS[w * 16 + g * 4 + r] = lrow[r];
    }
    __syncthreads();
#pragma unroll
    for (int qs = 0; qs < 4; ++qs) {
        f32x4 lv = *(const f32x4*)&lS[qs * 16 + g * 4];
#pragma unroll
        for (int dt = 0; dt < 4; ++dt) {
            int d = w * 64 + dt * 16 + r16;
#pragma unroll
            for (int r = 0; r < 4; ++r) {
                int q = qb * 64 + qs * 16 + g * 4 + r;
                zc[(size_t)q * (NHEADS * DHEAD) + h * DHEAD + d] =
                    f2b(Oacc[qs * 4 + dt][r] / lv[r]);
            }
        }
    }
}

// ---------------------------------------------------------------------------
// K3: out = zc @ lin_w^T + lin_b. A = zc_b [4096][1024], B = lw_b [1024][1024]
// (row n, contiguous k). fp32 output + bias. Same tiling as K1.
// ---------------------------------------------------------------------------
__global__ __launch_bounds__(256)
void out_gemm_kernel(const unsigned short* __restrict__ A,
                     const unsigned short* __restrict__ B,
                     const float* __restrict__ lb, float* __restrict__ out) {
    __shared__ unsigned short As[128 * 64];
    __shared__ unsigned short Bs[128 * 64];
    const int tid = threadIdx.x, w = tid >> 6, l = tid & 63;
    const int g = l >> 4, r16 = l & 15;
    const int m0 = blockIdx.x * 128, n0 = blockIdx.y * 128;
    const int wm = (w >> 1) * 64, wn = (w & 1) * 64;

    f32x4 acc[4][4];
#pragma unroll
    for (int mr = 0; mr < 4; ++mr)
#pragma unroll
        for (int nr = 0; nr < 4; ++nr) acc[mr][nr] = (f32x4){0.f, 0.f, 0.f, 0.f};

    for (int kb = 0; kb < DIM; kb += 64) {
        __syncthreads();
#pragma unroll
        for (int cc = 0; cc < 4; ++cc) {
            int row = w * 32 + cc * 8 + (l >> 3);
            int c = (l & 7) ^ (row & 7);
            gll16(&A[(size_t)(m0 + row) * DIM + kb + c * 8], &As[(size_t)(w * 32 + cc * 8) * 64]);
            gll16(&B[(size_t)(n0 + row) * DIM + kb + c * 8], &Bs[(size_t)(w * 32 + cc * 8) * 64]);
        }
        __syncthreads();
#pragma unroll
        for (int s = 0; s < 2; ++s) {
            bf16x8 af[4], bf[4];
#pragma unroll
            for (int mr = 0; mr < 4; ++mr) {
                int row = wm + mr * 16 + r16;
                int st = (s * 4 + g) ^ (row & 7);
                af[mr] = *(const bf16x8*)&As[row * 64 + st * 8];
            }
#pragma unroll
            for (int nr = 0; nr < 4; ++nr) {
                int row = wn + nr * 16 + r16;
                int st = (s * 4 + g) ^ (row & 7);
                bf[nr] = *(const bf16x8*)&Bs[row * 64 + st * 8];
            }
#pragma unroll
            for (int mr = 0; mr < 4; ++mr)
#pragma unroll
                for (int nr = 0; nr < 4; ++nr)
                    acc[mr][nr] = mfma16(af[mr], bf[nr], acc[mr][nr]);
        }
    }
#pragma unroll
    for (int mr = 0; mr < 4; ++mr)
#pragma unroll
        for (int nr = 0; nr < 4; ++nr) {
            int n = n0 + wn + nr * 16 + r16;
            float bv = lb[n];
#pragma unroll
            for (int r = 0; r < 4; ++r) {
                int m = m0 + wm + mr * 16 + g * 4 + r;
                out[(size_t)m * DIM + n] = acc[mr][nr][r] + bv;
            }
        }
}

// ---------------------------------------------------------------------------
extern "C" void kernel_launch(void* const* d_in, const int* in_sizes, int n_in,
                              void* d_out, int out_size, void* d_ws, size_t ws_size,
                              hipStream_t stream) {
    const float* x  = (const float*)d_in[0];   // [4096,1024]
    const float* Wq = (const float*)d_in[1];   // [4,1024,256]
    const float* lw = (const float*)d_in[2];   // [1024,1024]
    const float* lb = (const float*)d_in[3];   // [1024]
    float* out = (float*)d_out;                // [4096,1024] fp32

    char* wsb = (char*)d_ws;
    unsigned short* qkvb = (unsigned short*)(wsb);                    // 8 MB [4][4096][256]
    unsigned short* qkvT = (unsigned short*)(wsb + ((size_t)8 << 20)); // 8 MB [4][256][4096]
    unsigned short* xb   = (unsigned short*)(wsb + ((size_t)16 << 20)); // 8 MB [4096][1024]
    unsigned short* zcb  = xb;                                         // reuse after K1
    unsigned short* WqT  = (unsigned short*)(wsb + ((size_t)24 << 20)); // 2 MB [4][256][1024]
    unsigned short* lwb  = (unsigned short*)(wsb + ((size_t)26 << 20)); // 2 MB [1024][1024]

    conv_kernel<<<4096, 256, 0, stream>>>(x, xb, (SEQ * DIM) / 4);
    conv_kernel<<<1024, 256, 0, stream>>>(lw, lwb, (DIM * DIM) / 4);
    wqt_kernel<<<dim3(16, 4, 4), 256, 0, stream>>>(Wq, WqT);
    qkv_gemm_kernel<<<dim3(SEQ / 128, DIM / 128), 256, 0, stream>>>(xb, WqT, qkvb);
    qkvt_kernel<<<dim3(64, 4, 4), 256, 0, stream>>>(qkvb, qkvT);
    attn_kernel<<<dim3(SEQ / 64, NHEADS), 256, 0, stream>>>(qkvb, qkvT, zcb);
    out_gemm_kernel<<<dim3(SEQ / 128, DIM / 128), 256, 0, stream>>>(zcb, lwb, lb, out);
}

// Round 4
// 165.386 us; speedup vs baseline: 9.4491x; 1.5147x over previous
//
#include <hip/hip_runtime.h>
#include <math.h>

#define SEQ 4096
#define DIM 1024
#define DHEAD 256
#define NHEADS 4

typedef __attribute__((ext_vector_type(8))) short bf16x8;
typedef __attribute__((ext_vector_type(4))) float f32x4;
typedef __attribute__((ext_vector_type(4))) short short4v;
typedef __attribute__((ext_vector_type(8))) short short8v;

// fp32 -> bf16 round-to-nearest-even, as raw ushort bits
__device__ __forceinline__ unsigned short f2b(float f) {
    union { float f; unsigned u; } v; v.f = f;
    unsigned r = v.u + 0x7FFFu + ((v.u >> 16) & 1u);
    return (unsigned short)(r >> 16);
}
__device__ __forceinline__ float b2f(unsigned short u) {
    union { unsigned u; float f; } v; v.u = ((unsigned)u) << 16;
    return v.f;
}

// async global->LDS, 16B per lane; lds = wave-uniform base, g is per-lane
__device__ __forceinline__ void gll16(const void* g, void* lds) {
    __builtin_amdgcn_global_load_lds(
        (const __attribute__((address_space(1))) unsigned*)g,
        (__attribute__((address_space(3))) unsigned*)lds, 16, 0, 0);
}

__device__ __forceinline__ f32x4 mfma16(bf16x8 a, bf16x8 b, f32x4 c) {
    return __builtin_amdgcn_mfma_f32_16x16x32_bf16(a, b, c, 0, 0, 0);
}

// ---------------------------------------------------------------------------
// convert fp32 -> bf16, n4 float4's
// ---------------------------------------------------------------------------
__global__ __launch_bounds__(256)
void conv_kernel(const float* __restrict__ in, unsigned short* __restrict__ out, int n4) {
    int i = blockIdx.x * 256 + threadIdx.x;
    if (i >= n4) return;
    float4 v = ((const float4*)in)[i];
    short4v o;
    o[0] = (short)f2b(v.x); o[1] = (short)f2b(v.y);
    o[2] = (short)f2b(v.z); o[3] = (short)f2b(v.w);
    *(short4v*)(out + (size_t)i * 4) = o;
}

// ---------------------------------------------------------------------------
// Wq [4][1024][256] fp32 -> WqT [4][256][1024] bf16
// ---------------------------------------------------------------------------
__global__ __launch_bounds__(256)
void wqt_kernel(const float* __restrict__ Wq, unsigned short* __restrict__ WqT) {
    __shared__ unsigned short T[64][72];
    const int tid = threadIdx.x;
    const int h = blockIdx.z;
    const int d0 = blockIdx.x * 64, c0 = blockIdx.y * 64;
#pragma unroll
    for (int it = 0; it < 4; ++it) {
        int f = tid + 256 * it;
        int row = f >> 4, cg = f & 15;
        float4 v = *(const float4*)&Wq[((size_t)(h * DIM + d0 + row)) * DHEAD + c0 + cg * 4];
        T[row][cg * 4 + 0] = f2b(v.x); T[row][cg * 4 + 1] = f2b(v.y);
        T[row][cg * 4 + 2] = f2b(v.z); T[row][cg * 4 + 3] = f2b(v.w);
    }
    __syncthreads();
#pragma unroll
    for (int it = 0; it < 2; ++it) {
        int f = tid + 256 * it;
        int cl = f >> 3, dg = f & 7;
        short8v o;
#pragma unroll
        for (int e = 0; e < 8; ++e) o[e] = (short)T[dg * 8 + e][cl];
        *(short8v*)&WqT[((size_t)(h * DHEAD + c0 + cl)) * DIM + d0 + dg * 8] = o;
    }
}

// ---------------------------------------------------------------------------
// qkv [4][4096][256] bf16 -> qkvT [4][256][4096] bf16
// ---------------------------------------------------------------------------
__global__ __launch_bounds__(256)
void qkvt_kernel(const unsigned short* __restrict__ qkv, unsigned short* __restrict__ qkvT) {
    __shared__ unsigned short T[64][72];
    const int tid = threadIdx.x;
    const int h = blockIdx.z;
    const int r0 = blockIdx.x * 64, c0 = blockIdx.y * 64;
#pragma unroll
    for (int it = 0; it < 2; ++it) {
        int f = tid + 256 * it;
        int row = f >> 3, cg = f & 7;
        short8v v = *(const short8v*)&qkv[((size_t)h * SEQ + r0 + row) * DHEAD + c0 + cg * 8];
#pragma unroll
        for (int e = 0; e < 8; ++e) T[row][cg * 8 + e] = (unsigned short)v[e];
    }
    __syncthreads();
#pragma unroll
    for (int it = 0; it < 2; ++it) {
        int f = tid + 256 * it;
        int cl = f >> 3, rg = f & 7;
        short8v o;
#pragma unroll
        for (int e = 0; e < 8; ++e) o[e] = (short)T[rg * 8 + e][cl];
        *(short8v*)&qkvT[((size_t)h * DHEAD + c0 + cl) * SEQ + r0 + rg * 8] = o;
    }
}

// ---------------------------------------------------------------------------
// K1: qkv = x @ Wq  (bf16 MFMA, BM=BN=128, BK=64, out: qkv bf16 [4][4096][256])
// ---------------------------------------------------------------------------
__global__ __launch_bounds__(256)
void qkv_gemm_kernel(const unsigned short* __restrict__ A,
                     const unsigned short* __restrict__ B,
                     unsigned short* __restrict__ qkv) {
    __shared__ unsigned short As[128 * 64];
    __shared__ unsigned short Bs[128 * 64];
    const int tid = threadIdx.x, w = tid >> 6, l = tid & 63;
    const int g = l >> 4, r16 = l & 15;
    const int m0 = blockIdx.x * 128, n0 = blockIdx.y * 128;
    const int wm = (w >> 1) * 64, wn = (w & 1) * 64;

    f32x4 acc[4][4];
#pragma unroll
    for (int mr = 0; mr < 4; ++mr)
#pragma unroll
        for (int nr = 0; nr < 4; ++nr) acc[mr][nr] = (f32x4){0.f, 0.f, 0.f, 0.f};

    for (int kb = 0; kb < DIM; kb += 64) {
        __syncthreads();
#pragma unroll
        for (int cc = 0; cc < 4; ++cc) {
            int row = w * 32 + cc * 8 + (l >> 3);
            int c = (l & 7) ^ (row & 7);
            gll16(&A[(size_t)(m0 + row) * DIM + kb + c * 8], &As[(size_t)(w * 32 + cc * 8) * 64]);
            gll16(&B[(size_t)(n0 + row) * DIM + kb + c * 8], &Bs[(size_t)(w * 32 + cc * 8) * 64]);
        }
        __syncthreads();
#pragma unroll
        for (int s = 0; s < 2; ++s) {
            bf16x8 af[4], bf[4];
#pragma unroll
            for (int mr = 0; mr < 4; ++mr) {
                int row = wm + mr * 16 + r16;
                int st = (s * 4 + g) ^ (row & 7);
                af[mr] = *(const bf16x8*)&As[row * 64 + st * 8];
            }
#pragma unroll
            for (int nr = 0; nr < 4; ++nr) {
                int row = wn + nr * 16 + r16;
                int st = (s * 4 + g) ^ (row & 7);
                bf[nr] = *(const bf16x8*)&Bs[row * 64 + st * 8];
            }
#pragma unroll
            for (int mr = 0; mr < 4; ++mr)
#pragma unroll
                for (int nr = 0; nr < 4; ++nr)
                    acc[mr][nr] = mfma16(af[mr], bf[nr], acc[mr][nr]);
        }
    }
#pragma unroll
    for (int mr = 0; mr < 4; ++mr)
#pragma unroll
        for (int nr = 0; nr < 4; ++nr) {
            int n = n0 + wn + nr * 16 + r16;
            int h = n >> 8, c = n & 255;
#pragma unroll
            for (int r = 0; r < 4; ++r) {
                int m = m0 + wm + mr * 16 + g * 4 + r;
                qkv[((size_t)h * SEQ + m) * DHEAD + c] = f2b(acc[mr][nr][r]);
            }
        }
}

// ---------------------------------------------------------------------------
// K2: MFMA flash attention, split-K over 2 key halves, 2 blocks/CU.
// grid 512: bid&7 = (head<<1)|half (pins each (head,half) K/V stream to one
// XCD's L2), bid>>3 = q-block of 64 rows. 4 waves.
// QK^T swapped: S^T = mfma(K_frag, Q_frag) -> lane holds S[q=r16][16 j's]
// -> fully in-register online softmax (2+2 shfl_xor), P written to Ps as b64.
// PV: round-2-proven path (A = P from Ps, B = V from Vt tile), 16x16x32 MFMA.
// Epilogue: unnormalized partial O (bf16) + per-row (m,l) for the combiner.
// ---------------------------------------------------------------------------
__global__ __launch_bounds__(256, 2)
void attn_kernel(const unsigned short* __restrict__ qkv,
                 const unsigned short* __restrict__ qkvT,
                 unsigned short* __restrict__ p0,
                 unsigned short* __restrict__ p1,
                 float* __restrict__ ml) {
    __shared__ unsigned short Ks[64 * 256];  // row j: 32 chunks, st=(c&24)|((c&7)^(j&7))
    __shared__ unsigned short Vt[256 * 64];  // row d: 8 chunks, st=c^(d&7)
    __shared__ unsigned short Ps[64 * 64];   // row q: 8 chunks, st=c^(q&7)
    __shared__ float alphaS[64];
    __shared__ float mS[64], lS[64];

    const int tid = threadIdx.x, w = tid >> 6, l = tid & 63;
    const int g = l >> 4, r16 = l & 15;
    const int bid = blockIdx.x;
    const int h = (bid & 7) >> 1, hf = bid & 1;
    const int qb = bid >> 3;
    const unsigned short* __restrict__ qh = qkv + (size_t)h * SEQ * DHEAD;
    const unsigned short* __restrict__ qth = qkvT + (size_t)h * DHEAD * SEQ;
    const int jb0 = hf * (SEQ / 2);
    const int NT = (SEQ / 2) / 64;   // 32 key tiles per half

    // Q fragments (B-operand): lane q-row = qb*64 + w*16 + r16, d = 32s + 8g + e
    bf16x8 qf[8];
    {
        const unsigned short* qrow = qh + (size_t)(qb * 64 + w * 16 + r16) * DHEAD + g * 8;
#pragma unroll
        for (int s = 0; s < 8; ++s) qf[s] = *(const bf16x8*)(qrow + s * 32);
    }

    f32x4 Oacc[16];  // [qs*4+dt]: lane holds O[q = qs*16+4g+r][d = w*64+dt*16+r16]
#pragma unroll
    for (int i = 0; i < 16; ++i) Oacc[i] = (f32x4){0.f, 0.f, 0.f, 0.f};
    float mrow = -INFINITY, lrow = 0.f;   // for q = w*16 + r16 (same across g)

    for (int t = 0; t < NT; ++t) {
        const int jb = jb0 + t * 64;
        __syncthreads();   // prev iter's LDS reads done
        // stage K tile (row-major, chunk-swizzled) and V^T tile
#pragma unroll
        for (int cc = 0; cc < 8; ++cc) {
            int ch = w * 8 + cc;               // 1KB chunk, 2 rows of K
            int j = ch * 2 + (l >> 5);
            int cp = l & 31;
            int c = (cp & 24) | ((cp & 7) ^ (j & 7));
            gll16(&qh[(size_t)(jb + j) * DHEAD + c * 8], &Ks[(size_t)ch * 512]);
        }
#pragma unroll
        for (int cc = 0; cc < 8; ++cc) {
            int ch = w * 8 + cc;               // 1KB chunk, 8 rows of Vt
            int d = ch * 8 + (l >> 3);
            int c = (l & 7) ^ (d & 7);
            gll16(&qth[(size_t)d * SEQ + jb + c * 8], &Vt[(size_t)ch * 512]);
        }
        __syncthreads();   // staging visible (barrier drains vmcnt)

        // ---- S^T = K @ Q^T : lane gets S[q=r16][j = 16jt + 4g + r] ----
        f32x4 sacc[4];
#pragma unroll
        for (int jt = 0; jt < 4; ++jt) sacc[jt] = (f32x4){0.f, 0.f, 0.f, 0.f};
        __builtin_amdgcn_s_setprio(1);
#pragma unroll
        for (int s = 0; s < 8; ++s)
#pragma unroll
            for (int jt = 0; jt < 4; ++jt) {
                int j = jt * 16 + r16;
                int c = s * 4 + g;
                int st = (c & 24) | ((c & 7) ^ (j & 7));
                bf16x8 af = *(const bf16x8*)&Ks[j * 256 + st * 8];
                sacc[jt] = mfma16(af, qf[s], sacc[jt]);
            }
        __builtin_amdgcn_s_setprio(0);

        // ---- in-register online softmax (one q-row per lane) ----
        float mx = sacc[0][0];
#pragma unroll
        for (int jt = 0; jt < 4; ++jt)
#pragma unroll
            for (int r = 0; r < 4; ++r) mx = fmaxf(mx, sacc[jt][r]);
        mx = fmaxf(mx, __shfl_xor(mx, 16, 64));
        mx = fmaxf(mx, __shfl_xor(mx, 32, 64));

        float mn = fmaxf(mrow, mx);
        float alpha = __expf(mrow - mn);
        mrow = mn;

        float rsum = 0.f;
        short4v pf[4];
#pragma unroll
        for (int jt = 0; jt < 4; ++jt)
#pragma unroll
            for (int r = 0; r < 4; ++r) {
                float p = __expf(sacc[jt][r] - mrow);
                rsum += p;
                pf[jt][r] = (short)f2b(p);
            }
        rsum += __shfl_xor(rsum, 16, 64);
        rsum += __shfl_xor(rsum, 32, 64);
        lrow = lrow * alpha + rsum;

        // P -> Ps: row q = w*16+r16, j = jt*16 + g*4 + {0..3}; chunk = (j>>3)^(q&7)
#pragma unroll
        for (int jt = 0; jt < 4; ++jt) {
            int st = (jt * 2 + (g >> 1)) ^ (r16 & 7);
            *(short4v*)&Ps[(w * 16 + r16) * 64 + st * 8 + (g & 1) * 4] = pf[jt];
        }
        if (g == 0) alphaS[w * 16 + r16] = alpha;
        __syncthreads();   // Ps + alphaS visible

        // ---- O += P @ V on all 64 q-rows x this wave's 64-wide d-slice ----
        bf16x8 pa[8];
#pragma unroll
        for (int qs = 0; qs < 4; ++qs) {
            f32x4 av = *(const f32x4*)&alphaS[qs * 16 + g * 4];
#pragma unroll
            for (int dt = 0; dt < 4; ++dt)
#pragma unroll
                for (int r = 0; r < 4; ++r) Oacc[qs * 4 + dt][r] *= av[r];
#pragma unroll
            for (int s2 = 0; s2 < 2; ++s2) {
                int qrow = qs * 16 + r16;
                int st = (s2 * 4 + g) ^ (qrow & 7);
                pa[qs * 2 + s2] = *(const bf16x8*)&Ps[qrow * 64 + st * 8];
            }
        }
        __builtin_amdgcn_s_setprio(1);
#pragma unroll
        for (int dt = 0; dt < 4; ++dt) {
            int d = w * 64 + dt * 16 + r16;
#pragma unroll
            for (int s2 = 0; s2 < 2; ++s2) {
                int st = (s2 * 4 + g) ^ (d & 7);
                bf16x8 bv = *(const bf16x8*)&Vt[d * 64 + st * 8];
#pragma unroll
                for (int qs = 0; qs < 4; ++qs)
                    Oacc[qs * 4 + dt] = mfma16(pa[qs * 2 + s2], bv, Oacc[qs * 4 + dt]);
            }
        }
        __builtin_amdgcn_s_setprio(0);
    }

    // ---- epilogue: unnormalized partial O (bf16) + per-row (m, l) ----
    if (g == 0) { mS[w * 16 + r16] = mrow; lS[w * 16 + r16] = lrow; }
    __syncthreads();
    unsigned short* po = hf ? p1 : p0;
#pragma unroll
    for (int qs = 0; qs < 4; ++qs)
#pragma unroll
        for (int dt = 0; dt < 4; ++dt) {
            int d = w * 64 + dt * 16 + r16;
#pragma unroll
            for (int r = 0; r < 4; ++r) {
                int q = qb * 64 + qs * 16 + g * 4 + r;
                po[(size_t)q * (NHEADS * DHEAD) + h * DHEAD + d] = f2b(Oacc[qs * 4 + dt][r]);
            }
        }
    if (tid < 64) {
        int q = qb * 64 + tid;
        float* mlq = ml + ((size_t)(hf * NHEADS + h) * SEQ + q) * 2;
        mlq[0] = mS[tid]; mlq[1] = lS[tid];
    }
}

// ---------------------------------------------------------------------------
// K2b: combine the two key-halves:
// out = (e0*acc0 + e1*acc1) / (e0*l0 + e1*l1),  e_i = exp(m_i - max(m0,m1))
// ---------------------------------------------------------------------------
__global__ __launch_bounds__(256)
void combine_kernel(const unsigned short* __restrict__ pa,
                    const unsigned short* __restrict__ pb,
                    const float* __restrict__ ml,
                    unsigned short* __restrict__ zc) {
    size_t t = (size_t)blockIdx.x * 256 + threadIdx.x;
    size_t f = t * 8;
    int q = (int)(f >> 10);
    int h = (int)((f >> 8) & 3);
    const float* ml0 = ml + ((size_t)h * SEQ + q) * 2;
    const float* ml1 = ml + ((size_t)(NHEADS + h) * SEQ + q) * 2;
    float m0 = ml0[0], l0 = ml0[1], m1 = ml1[0], l1 = ml1[1];
    float M = fmaxf(m0, m1);
    float e0 = __expf(m0 - M), e1 = __expf(m1 - M);
    float inv = 1.f / (e0 * l0 + e1 * l1);
    e0 *= inv; e1 *= inv;
    short8v a = *(const short8v*)(pa + f);
    short8v b = *(const short8v*)(pb + f);
    short8v o;
#pragma unroll
    for (int e = 0; e < 8; ++e)
        o[e] = (short)f2b(e0 * b2f((unsigned short)a[e]) + e1 * b2f((unsigned short)b[e]));
    *(short8v*)(zc + f) = o;
}

// ---------------------------------------------------------------------------
// K3: out = zc @ lin_w^T + lin_b  (fp32 out + bias)
// ---------------------------------------------------------------------------
__global__ __launch_bounds__(256)
void out_gemm_kernel(const unsigned short* __restrict__ A,
                     const unsigned short* __restrict__ B,
                     const float* __restrict__ lb, float* __restrict__ out) {
    __shared__ unsigned short As[128 * 64];
    __shared__ unsigned short Bs[128 * 64];
    const int tid = threadIdx.x, w = tid >> 6, l = tid & 63;
    const int g = l >> 4, r16 = l & 15;
    const int m0 = blockIdx.x * 128, n0 = blockIdx.y * 128;
    const int wm = (w >> 1) * 64, wn = (w & 1) * 64;

    f32x4 acc[4][4];
#pragma unroll
    for (int mr = 0; mr < 4; ++mr)
#pragma unroll
        for (int nr = 0; nr < 4; ++nr) acc[mr][nr] = (f32x4){0.f, 0.f, 0.f, 0.f};

    for (int kb = 0; kb < DIM; kb += 64) {
        __syncthreads();
#pragma unroll
        for (int cc = 0; cc < 4; ++cc) {
            int row = w * 32 + cc * 8 + (l >> 3);
            int c = (l & 7) ^ (row & 7);
            gll16(&A[(size_t)(m0 + row) * DIM + kb + c * 8], &As[(size_t)(w * 32 + cc * 8) * 64]);
            gll16(&B[(size_t)(n0 + row) * DIM + kb + c * 8], &Bs[(size_t)(w * 32 + cc * 8) * 64]);
        }
        __syncthreads();
#pragma unroll
        for (int s = 0; s < 2; ++s) {
            bf16x8 af[4], bf[4];
#pragma unroll
            for (int mr = 0; mr < 4; ++mr) {
                int row = wm + mr * 16 + r16;
                int st = (s * 4 + g) ^ (row & 7);
                af[mr] = *(const bf16x8*)&As[row * 64 + st * 8];
            }
#pragma unroll
            for (int nr = 0; nr < 4; ++nr) {
                int row = wn + nr * 16 + r16;
                int st = (s * 4 + g) ^ (row & 7);
                bf[nr] = *(const bf16x8*)&Bs[row * 64 + st * 8];
            }
#pragma unroll
            for (int mr = 0; mr < 4; ++mr)
#pragma unroll
                for (int nr = 0; nr < 4; ++nr)
                    acc[mr][nr] = mfma16(af[mr], bf[nr], acc[mr][nr]);
        }
    }
#pragma unroll
    for (int mr = 0; mr < 4; ++mr)
#pragma unroll
        for (int nr = 0; nr < 4; ++nr) {
            int n = n0 + wn + nr * 16 + r16;
            float bv = lb[n];
#pragma unroll
            for (int r = 0; r < 4; ++r) {
                int m = m0 + wm + mr * 16 + g * 4 + r;
                out[(size_t)m * DIM + n] = acc[mr][nr][r] + bv;
            }
        }
}

// ---------------------------------------------------------------------------
extern "C" void kernel_launch(void* const* d_in, const int* in_sizes, int n_in,
                              void* d_out, int out_size, void* d_ws, size_t ws_size,
                              hipStream_t stream) {
    const float* x  = (const float*)d_in[0];   // [4096,1024]
    const float* Wq = (const float*)d_in[1];   // [4,1024,256]
    const float* lw = (const float*)d_in[2];   // [1024,1024]
    const float* lb = (const float*)d_in[3];   // [1024]
    float* out = (float*)d_out;                // [4096,1024] fp32

    char* wsb = (char*)d_ws;
    unsigned short* qkvb = (unsigned short*)(wsb);                      // [0,8)MB  [4][4096][256]
    unsigned short* qkvT = (unsigned short*)(wsb + ((size_t)8 << 20));  // [8,16)   [4][256][4096]
    unsigned short* xb   = (unsigned short*)(wsb + ((size_t)16 << 20)); // [16,24)  x bf16 -> p0/zc
    unsigned short* p0   = xb;                                          //          (post qkv_gemm)
    unsigned short* WqT  = (unsigned short*)(wsb + ((size_t)24 << 20)); // [24,26)  WqT bf16
    float*          ml   = (float*)(wsb + ((size_t)24 << 20));          //          reused post qkv_gemm
    unsigned short* lwb  = (unsigned short*)(wsb + ((size_t)26 << 20)); // [26,28)  lin_w bf16
    unsigned short* p1   = (unsigned short*)d_out;  // half-1 partial parks in d_out
                                                    // (dead until out_gemm, which runs last)

    conv_kernel<<<4096, 256, 0, stream>>>(x, xb, (SEQ * DIM) / 4);
    conv_kernel<<<1024, 256, 0, stream>>>(lw, lwb, (DIM * DIM) / 4);
    wqt_kernel<<<dim3(16, 4, 4), 256, 0, stream>>>(Wq, WqT);
    qkv_gemm_kernel<<<dim3(SEQ / 128, DIM / 128), 256, 0, stream>>>(xb, WqT, qkvb);
    qkvt_kernel<<<dim3(64, 4, 4), 256, 0, stream>>>(qkvb, qkvT);
    attn_kernel<<<512, 256, 0, stream>>>(qkvb, qkvT, p0, p1, ml);
    combine_kernel<<<(SEQ * DIM / 8) / 256, 256, 0, stream>>>(p0, p1, ml, p0);
    out_gemm_kernel<<<dim3(SEQ / 128, DIM / 128), 256, 0, stream>>>(p0, lwb, lb, out);
}